// Round 8
// baseline (887.807 us; speedup 1.0000x reference)
//
#include <hip/hip_runtime.h>

typedef unsigned short u16;
typedef unsigned int   u32;
typedef __attribute__((ext_vector_type(8))) short short8;
typedef __attribute__((ext_vector_type(4))) short short4v;
typedef __attribute__((ext_vector_type(4))) float f32x4;

#define N_NODES 100000
#define NQ      128
#define DD      128
#define NE      131072
#define OO      256   // 2*D

__device__ __forceinline__ float b2f(u16 b){ u32 u = ((u32)b) << 16; return __uint_as_float(u); }
__device__ __forceinline__ u16 f2b(float f){ u32 u = __float_as_uint(f); u32 r = (u + 0x7FFFu + ((u >> 16) & 1u)) >> 16; return (u16)r; }
__device__ __forceinline__ float lrelu(float x){ return x > 0.0f ? x : 0.01f * x; }
__device__ __forceinline__ u32 fenc(float f){ u32 u = __float_as_uint(f); return (u & 0x80000000u) ? ~u : (u | 0x80000000u); }
__device__ __forceinline__ float fdec(u32 e){ u32 u = (e & 0x80000000u) ? (e & 0x7FFFFFFFu) : ~e; return __uint_as_float(u); }

__device__ __forceinline__ void stage4(f32x4 v, u16* dhi, u16* dlo){
  short4v h4, l4;
  #pragma unroll
  for (int i = 0; i < 4; ++i){
    u16 h = f2b(v[i]); h4[i] = (short)h; l4[i] = (short)f2b(v[i] - b2f(h));
  }
  *(short4v*)dhi = h4; *(short4v*)dlo = l4;
}

// ---------------- W split: all four weights, one launch ------------------------
#define SPL_N1 (256*512)
#define SPL_N2 (256*512)
#define SPL_N3 (256*256)
#define SPL_N4 (128*128)
__global__ void split_all_kernel(
    const float* __restrict__ Wl, const float* __restrict__ Wr,
    const float* __restrict__ Wc, const float* __restrict__ Ws,
    u16* __restrict__ WlH, u16* __restrict__ WlL,
    u16* __restrict__ WrH, u16* __restrict__ WrL,
    u16* __restrict__ WcH, u16* __restrict__ WcL,
    u16* __restrict__ WsH, u16* __restrict__ WsL)
{
  int i = blockIdx.x*256 + threadIdx.x;
  const float* src; u16 *hi, *lo; int k = i;
  if (k < SPL_N1){ src = Wl; hi = WlH; lo = WlL; }
  else if ((k -= SPL_N1) < SPL_N2){ src = Wr; hi = WrH; lo = WrL; }
  else if ((k -= SPL_N2) < SPL_N3){ src = Wc; hi = WcH; lo = WcL; }
  else if ((k -= SPL_N3) < SPL_N4){ src = Ws; hi = WsH; lo = WsL; }
  else return;
  float x = src[k];
  u16 h = f2b(x);
  hi[k] = h;
  lo[k] = f2b(x - b2f(h));
}

// ---------------- K0: per-query tables (exact f32) ----------------------------
__global__ __launch_bounds__(256) void qtable_kernel(
    const float* __restrict__ qsrc, const float* __restrict__ qrel,
    const float* __restrict__ Wl, const float* __restrict__ bl,
    const float* __restrict__ Wr, const float* __restrict__ br,
    float* __restrict__ Qlt, float* __restrict__ Qrt)
{
  int b = blockIdx.x; int side = b >> 7; int q = b & 127; int o = threadIdx.x;
  __shared__ __align__(16) float s[2*DD];
  if (threadIdx.x < DD) s[threadIdx.x] = qsrc[q*DD + threadIdx.x];
  else                  s[threadIdx.x] = qrel[q*DD + threadIdx.x - DD];
  __syncthreads();
  const float* W    = side ? Wr : Wl;
  const float* bias = side ? br : bl;
  float acc = bias[o];
  const float* wrow = W + (size_t)o*512 + 256;
  #pragma unroll 4
  for (int k4 = 0; k4 < 64; ++k4){
    f32x4 wv = *(const f32x4*)(wrow + k4*4);
    f32x4 sv = *(const f32x4*)(s + k4*4);
    acc += sv[0]*wv[0]; acc += sv[1]*wv[1]; acc += sv[2]*wv[2]; acc += sv[3]*wv[3];
  }
  (side ? Qrt : Qlt)[q*OO + o] = acc;
}

// ---------------- K1: fused edge bilinear -> logits (hi/lo 3-term MFMA) -------
// v5: BM=48, 512 threads, LDS ~54 KB -> 3 blocks/CU -> 6 waves/SIMD.
// Tail block (NE % 48 = 32) handled with gather/write guards.
// Term-major MFMA order preserves per-accumulator FP order (bit-identical).
#define BM   48
#define RSTc 264
#define HST  136

template<int WS, int PF>
__device__ __forceinline__ void gemm8(f32x4 (&ACC)[3][2],
    const u16* __restrict__ WH, const u16* __restrict__ WL,
    const u16* A0H, const u16* A0L, const u16* A1H, const u16* A1L, int ASTR,
    int ow, int ln, int qd)
{
  short8 nbh[2], nbl[2];
  if (PF){
    #pragma unroll
    for (int nt = 0; nt < 2; ++nt){ int o = ow + nt*16 + ln;
      nbh[nt] = *(const short8*)(WH + (size_t)o*WS + qd*8);
      nbl[nt] = *(const short8*)(WL + (size_t)o*WS + qd*8);
    }
  }
  #pragma unroll
  for (int c = 0; c < 8; ++c){
    short8 bh[2], bl[2], ah[3], al[3];
    if (PF){
      #pragma unroll
      for (int nt = 0; nt < 2; ++nt){ bh[nt] = nbh[nt]; bl[nt] = nbl[nt]; }
      if (c < 7){
        #pragma unroll
        for (int nt = 0; nt < 2; ++nt){ int o = ow + nt*16 + ln;
          nbh[nt] = *(const short8*)(WH + (size_t)o*WS + (c+1)*32 + qd*8);
          nbl[nt] = *(const short8*)(WL + (size_t)o*WS + (c+1)*32 + qd*8);
        }
      }
    } else {
      #pragma unroll
      for (int nt = 0; nt < 2; ++nt){ int o = ow + nt*16 + ln;
        bh[nt] = *(const short8*)(WH + (size_t)o*WS + c*32 + qd*8);
        bl[nt] = *(const short8*)(WL + (size_t)o*WS + c*32 + qd*8);
      }
    }
    const u16* hs = (c < 4) ? A0H : A1H;
    const u16* ls = (c < 4) ? A0L : A1L;
    int cc = (c < 4) ? c : c - 4;
    #pragma unroll
    for (int mt = 0; mt < 3; ++mt){
      int base = (mt*16 + ln)*ASTR + cc*32 + qd*8;
      ah[mt] = *(const short8*)&hs[base];
      al[mt] = *(const short8*)&ls[base];
    }
    #pragma unroll
    for (int mt = 0; mt < 3; ++mt)
      #pragma unroll
      for (int nt = 0; nt < 2; ++nt)
        ACC[mt][nt] = __builtin_amdgcn_mfma_f32_16x16x32_bf16(ah[mt], bh[nt], ACC[mt][nt], 0, 0, 0);
    #pragma unroll
    for (int mt = 0; mt < 3; ++mt)
      #pragma unroll
      for (int nt = 0; nt < 2; ++nt)
        ACC[mt][nt] = __builtin_amdgcn_mfma_f32_16x16x32_bf16(ah[mt], bl[nt], ACC[mt][nt], 0, 0, 0);
    #pragma unroll
    for (int mt = 0; mt < 3; ++mt)
      #pragma unroll
      for (int nt = 0; nt < 2; ++nt)
        ACC[mt][nt] = __builtin_amdgcn_mfma_f32_16x16x32_bf16(al[mt], bh[nt], ACC[mt][nt], 0, 0, 0);
  }
}

__global__ __launch_bounds__(512, 4) void edge_logits_kernel(
    const float* __restrict__ node_rep, const float* __restrict__ rel_emb,
    const u16* __restrict__ WlH, const u16* __restrict__ WlL,
    const u16* __restrict__ WrH, const u16* __restrict__ WrL,
    const u16* __restrict__ WcH, const u16* __restrict__ WcL,
    const float* __restrict__ bcb,
    const float* __restrict__ Qlt, const float* __restrict__ Qrt,
    const int* __restrict__ idx_i, const int* __restrict__ idx_j, const int* __restrict__ qidx,
    float* __restrict__ logits, u32* __restrict__ segmax, int* __restrict__ qcount)
{
  __shared__ __align__(16) u16 bufA[2*BM*HST];  // Hj -> Hi -> RRhi
  __shared__ __align__(16) u16 bufB[2*BM*HST];  // Rel -> RRlo
  __shared__ int qidS[BM];
  __shared__ float lpart[8][BM];

  u16* HjHi = bufA;  u16* HjLo = bufA + BM*HST;
  u16* ReHi = bufB;  u16* ReLo = bufB + BM*HST;
  u16* RRhi = bufA;  u16* RRlo = bufB;

  const int tid = threadIdx.x;
  const int e0 = blockIdx.x * BM;
  const int lane = tid & 63, w = tid >> 6;
  const int ln = lane & 15, qd = lane >> 4;
  const int ow = w * 32;

  if (tid < BM) qidS[tid] = (e0 + tid < NE) ? qidx[e0 + tid] : 0;

  // stage Hj + Rel into LDS (hi/lo split); BM*32 = 1536 slots over 512 thr x 3
  #pragma unroll
  for (int it = 0; it < 3; ++it){
    int c = tid + it*512;
    int r = c >> 5, seg = (c & 31) << 2;
    int e = e0 + r;
    int j  = (e < NE) ? idx_j[e] : 0;
    int re = (e < NE) ? e : 0;
    f32x4 vj = *(const f32x4*)(node_rep + (size_t)j*DD + seg);
    f32x4 vr = *(const f32x4*)(rel_emb + (size_t)re*DD + seg);
    stage4(vj, &HjHi[r*HST + seg], &HjLo[r*HST + seg]);
    stage4(vr, &ReHi[r*HST + seg], &ReLo[r*HST + seg]);
  }
  // pre-gather Hi rows into registers (latency hides under right GEMM)
  f32x4 hipre[3];
  #pragma unroll
  for (int it = 0; it < 3; ++it){
    int c = tid + it*512;
    int r = c >> 5, seg = (c & 31) << 2;
    int e = e0 + r;
    int ii = (e < NE) ? idx_i[e] : 0;
    hipre[it] = *(const f32x4*)(node_rep + (size_t)ii*DD + seg);
  }
  __syncthreads();

  // ---- right GEMM: acc = [Hj|Rel] @ Wr^T ----
  f32x4 acc[3][2];
  #pragma unroll
  for (int mt = 0; mt < 3; ++mt)
    #pragma unroll
    for (int nt = 0; nt < 2; ++nt) acc[mt][nt] = (f32x4){0.f,0.f,0.f,0.f};
  gemm8<512, 1>(acc, WrH, WrL, HjHi, HjLo, ReHi, ReLo, HST, ow, ln, qd);
  __syncthreads();   // all waves done reading Hj

  // restage Hi from registers into bufA (over Hj)
  #pragma unroll
  for (int it = 0; it < 3; ++it){
    int c = tid + it*512;
    int r = c >> 5, seg = (c & 31) << 2;
    stage4(hipre[it], &HjHi[r*HST + seg], &HjLo[r*HST + seg]);
  }
  __syncthreads();

  // ---- left GEMM: lacc = [Hi|Rel] @ Wl^T ----
  f32x4 lacc[3][2];
  #pragma unroll
  for (int mt = 0; mt < 3; ++mt)
    #pragma unroll
    for (int nt = 0; nt < 2; ++nt) lacc[mt][nt] = (f32x4){0.f,0.f,0.f,0.f};
  gemm8<512, 0>(lacc, WlH, WlL, HjHi, HjLo, ReHi, ReLo, HST, ow, ln, qd);
  __syncthreads();   // Hi/Rel dead; RR may overlay bufA/bufB

  // epilogue: RR = leaky(acc + Qright[qid][col]); split into hi/lo in LDS
  #pragma unroll
  for (int mt = 0; mt < 3; ++mt)
    #pragma unroll
    for (int nt = 0; nt < 2; ++nt){
      int col = ow + nt*16 + ln;
      #pragma unroll
      for (int rg = 0; rg < 4; ++rg){
        int row = mt*16 + qd*4 + rg;
        float v = acc[mt][nt][rg] + Qrt[qidS[row]*OO + col];
        v = lrelu(v);
        u16 hi = f2b(v);
        RRhi[row*RSTc + col] = hi;
        RRlo[row*RSTc + col] = f2b(v - b2f(hi));
      }
    }
  __syncthreads();

  // ---- center GEMM: racc = (RRhi+RRlo) @ Wc^T ----
  f32x4 racc[3][2];
  #pragma unroll
  for (int mt = 0; mt < 3; ++mt)
    #pragma unroll
    for (int nt = 0; nt < 2; ++nt) racc[mt][nt] = (f32x4){0.f,0.f,0.f,0.f};
  gemm8<256, 1>(racc, WcH, WcL, RRhi, RRlo, RRhi + 128, RRlo + 128, RSTc, ow, ln, qd);

  // fused logits dot: sum_o leaky(L) * (R + b_center)
  float bcv[2];
  #pragma unroll
  for (int nt = 0; nt < 2; ++nt) bcv[nt] = bcb[ow + nt*16 + ln];

  float part[3][4];
  #pragma unroll
  for (int mt = 0; mt < 3; ++mt)
    #pragma unroll
    for (int rg = 0; rg < 4; ++rg) part[mt][rg] = 0.f;

  #pragma unroll
  for (int mt = 0; mt < 3; ++mt)
    #pragma unroll
    for (int nt = 0; nt < 2; ++nt){
      int col = ow + nt*16 + ln;
      #pragma unroll
      for (int rg = 0; rg < 4; ++rg){
        int row = mt*16 + qd*4 + rg;
        float lv = lacc[mt][nt][rg] + Qlt[qidS[row]*OO + col];
        lv = lrelu(lv);
        float rv = racc[mt][nt][rg] + bcv[nt];
        part[mt][rg] += lv * rv;
      }
    }

  #pragma unroll
  for (int mt = 0; mt < 3; ++mt)
    #pragma unroll
    for (int rg = 0; rg < 4; ++rg){
      float p = part[mt][rg];
      p += __shfl_xor(p, 1); p += __shfl_xor(p, 2);
      p += __shfl_xor(p, 4); p += __shfl_xor(p, 8);
      if (ln == 0) lpart[w][mt*16 + qd*4 + rg] = p;
    }
  __syncthreads();
  if (tid < BM && e0 + tid < NE){
    float lg = lpart[0][tid] + lpart[1][tid] + lpart[2][tid] + lpart[3][tid]
             + lpart[4][tid] + lpart[5][tid] + lpart[6][tid] + lpart[7][tid];
    int e = e0 + tid;
    logits[e] = lg;
    atomicMax(segmax + idx_i[e], fenc(lg));   // fused seg_max_count
    atomicAdd(qcount + qidx[e], 1);
  }
}

// ---------------- K2: segment exp + denom sum ----------------------------------
__global__ void seg_exp_sum_kernel(const float* __restrict__ logits,
    const int* __restrict__ idx_i, const u32* __restrict__ segmax,
    float* __restrict__ ex, float* __restrict__ denom)
{
  int e = blockIdx.x*256 + threadIdx.x; if (e >= NE) return;
  int i = idx_i[e];
  float d = fminf(logits[e] - fdec(segmax[i]), 0.0f);
  float v = expf(d);
  ex[e] = v;
  atomicAdd(denom + i, v);
}

// ---------------- K3: scan of query counts -------------------------------------
__global__ void scan_kernel(const int* __restrict__ qcount,
                            int* __restrict__ qstart, int* __restrict__ qcursor)
{
  if (blockIdx.x == 0 && threadIdx.x == 0){
    int acc = 0;
    for (int i = 0; i < NQ; ++i){ qstart[i] = acc; qcursor[i] = acc; acc += qcount[i]; }
  }
}

// ---------------- K4: fused attn/target + bucket fill --------------------------
__global__ void attn_bucket_kernel(const float* __restrict__ ex,
    const float* __restrict__ denom, const int* __restrict__ idx_i,
    const float* __restrict__ visited, const int* __restrict__ qidx,
    int* __restrict__ qcursor, int* __restrict__ bucket,
    float* __restrict__ attn, float* __restrict__ target)
{
  int e = blockIdx.x*256 + threadIdx.x; if (e >= NE) return;
  int i = idx_i[e];
  float a = ex[e] / fmaxf(denom[i], 1e-30f);
  attn[e] = a;
  target[e] = a * visited[i];
  int p = atomicAdd(qcursor + qidx[e], 1);
  bucket[p] = e;
}

// ---------------- K5: exact per-group top-k (count-beats, lexsort-stable) ------
#define TOPK_CAP 2560
__global__ __launch_bounds__(1024) void topk_kernel(
    const int* __restrict__ qcount, const int* __restrict__ qstart,
    const int* __restrict__ bucket, const float* __restrict__ target,
    const int* __restrict__ maxe_p, int* __restrict__ keep)
{
  __shared__ float ss[TOPK_CAP];
  __shared__ int   se[TOPK_CAP];
  int q = blockIdx.x;
  int m = qcount[q], start = qstart[q];
  int maxe = *maxe_p;
  if (maxe <= 0 || maxe > (1 << 30)){
    float f = __int_as_float(maxe);
    if (f > 0.0f && f < 1.0e9f) maxe = (int)f;
  }
  int tid = threadIdx.x;
  if (m <= maxe){
    for (int i = tid; i < m; i += 1024) keep[bucket[start + i]] = 1;
    return;
  }
  if (m <= TOPK_CAP){
    for (int i = tid; i < m; i += 1024){
      int e = bucket[start + i]; ss[i] = target[e]; se[i] = e;
    }
    __syncthreads();
    for (int i = tid; i < m; i += 1024){
      float s = ss[i]; int eid = se[i]; int cnt = 0;
      for (int j = 0; j < m; ++j){
        float sj = ss[j]; int ej = se[j];
        cnt += (sj > s) || (sj == s && ej < eid);
      }
      keep[eid] = (cnt < maxe) ? 1 : 0;
    }
  } else {
    for (int i = tid; i < m; i += 1024){
      int eid = bucket[start + i]; float s = target[eid]; int cnt = 0;
      for (int j = 0; j < m; ++j){
        int ej = bucket[start + j]; float sj = target[ej];
        cnt += (sj > s) || (sj == s && ej < eid);
      }
      keep[eid] = (cnt < maxe) ? 1 : 0;
    }
  }
}

// ---------------- K5b: merged scatter: score + attn-weighted hi -----------------
__global__ __launch_bounds__(256) void edge_scatter_kernel(
    const int* __restrict__ keep, const float* __restrict__ attn,
    const float* __restrict__ target,
    const int* __restrict__ idx_i, const int* __restrict__ idx_j,
    const float* __restrict__ node_rep,
    float* __restrict__ out_score, float* __restrict__ agg)
{
  int wid = (blockIdx.x * 256 + threadIdx.x) >> 6;
  if (wid >= NE) return;
  if (!keep[wid]) return;                 // wave-uniform
  int lane = threadIdx.x & 63;
  int ii = idx_i[wid], jj = idx_j[wid];
  float a = attn[wid];
  if (lane == 0) atomicAdd(out_score + jj, target[wid]);
  float h0 = node_rep[(size_t)ii*DD + lane];
  float h1 = node_rep[(size_t)ii*DD + 64 + lane];
  atomicAdd(agg + (size_t)jj*DD + lane,      a*h0);
  atomicAdd(agg + (size_t)jj*DD + 64 + lane, a*h1);
}

// ---------------- K6: out_rep = leaky((node_rep+agg) @ Wstep^T + bstep), MFMA ---
// agg aliases out_rep: each block reads its 64 rows into LDS (before barrier),
// then overwrites the same rows. Rows are disjoint across blocks -> safe.
__global__ __launch_bounds__(256) void final_mfma_kernel(
    const float* __restrict__ node_rep, const float* __restrict__ aggc,
    const u16* __restrict__ WsH, const u16* __restrict__ WsL,
    const float* __restrict__ bstep, float* __restrict__ out_rep)
{
  __shared__ __align__(16) u16 Ahi[64*HST];
  __shared__ __align__(16) u16 Alo[64*HST];
  const int tid = threadIdx.x;
  const int m0 = blockIdx.x * 64;

  for (int c = tid; c < 64*32; c += 256){
    int r = c >> 5, seg = (c & 31) << 2;
    int m = m0 + r;
    float v[4];
    if (m < N_NODES){
      const float* nr = node_rep + (size_t)m*DD + seg;
      const float* ag = aggc + (size_t)m*DD + seg;
      #pragma unroll
      for (int i = 0; i < 4; ++i) v[i] = nr[i] + ag[i];
    } else {
      #pragma unroll
      for (int i = 0; i < 4; ++i) v[i] = 0.f;
    }
    short4v h4, l4;
    #pragma unroll
    for (int i = 0; i < 4; ++i){
      u16 h = f2b(v[i]); h4[i] = (short)h; l4[i] = (short)f2b(v[i] - b2f(h));
    }
    *(short4v*)&Ahi[r*HST + seg] = h4;
    *(short4v*)&Alo[r*HST + seg] = l4;
  }
  __syncthreads();

  const int lane = tid & 63, w = tid >> 6;
  const int ln = lane & 15, qd = lane >> 4;
  const int ow = w * 32;

  short8 bh[2][4], bl[2][4];
  #pragma unroll
  for (int nt = 0; nt < 2; ++nt)
    #pragma unroll
    for (int c = 0; c < 4; ++c){
      int o = ow + nt*16 + ln;
      bh[nt][c] = *(const short8*)(WsH + (size_t)o*DD + c*32 + qd*8);
      bl[nt][c] = *(const short8*)(WsL + (size_t)o*DD + c*32 + qd*8);
    }

  f32x4 acc[4][2];
  #pragma unroll
  for (int mt = 0; mt < 4; ++mt)
    #pragma unroll
    for (int nt = 0; nt < 2; ++nt) acc[mt][nt] = (f32x4){0.f,0.f,0.f,0.f};

  #pragma unroll
  for (int mt = 0; mt < 4; ++mt)
    #pragma unroll
    for (int c = 0; c < 4; ++c){
      int base = (mt*16 + ln)*HST + c*32 + qd*8;
      short8 ah = *(const short8*)&Ahi[base];
      short8 al = *(const short8*)&Alo[base];
      #pragma unroll
      for (int nt = 0; nt < 2; ++nt){
        acc[mt][nt] = __builtin_amdgcn_mfma_f32_16x16x32_bf16(ah, bh[nt][c], acc[mt][nt], 0, 0, 0);
        acc[mt][nt] = __builtin_amdgcn_mfma_f32_16x16x32_bf16(ah, bl[nt][c], acc[mt][nt], 0, 0, 0);
        acc[mt][nt] = __builtin_amdgcn_mfma_f32_16x16x32_bf16(al, bh[nt][c], acc[mt][nt], 0, 0, 0);
      }
    }

  #pragma unroll
  for (int mt = 0; mt < 4; ++mt)
    #pragma unroll
    for (int nt = 0; nt < 2; ++nt){
      int col = ow + nt*16 + ln;
      float bs = bstep[col];
      #pragma unroll
      for (int rg = 0; rg < 4; ++rg){
        int m = m0 + mt*16 + qd*4 + rg;
        if (m < N_NODES)
          out_rep[(size_t)m*DD + col] = lrelu(acc[mt][nt][rg] + bs);
      }
    }
}

// ---------------- host ---------------------------------------------------------
extern "C" void kernel_launch(void* const* d_in, const int* in_sizes, int n_in,
                              void* d_out, int out_size, void* d_ws, size_t ws_size,
                              hipStream_t stream)
{
  const float* visited  = (const float*)d_in[0];
  const float* node_rep = (const float*)d_in[1];
  const float* qsrc     = (const float*)d_in[2];
  const float* qrel     = (const float*)d_in[3];
  const float* rel_emb  = (const float*)d_in[4];
  const float* Wl       = (const float*)d_in[5];
  const float* bl       = (const float*)d_in[6];
  const float* Wr       = (const float*)d_in[7];
  const float* br       = (const float*)d_in[8];
  const float* Wc       = (const float*)d_in[9];
  const float* bcb      = (const float*)d_in[10];
  const float* Wstep    = (const float*)d_in[11];
  const float* bstep    = (const float*)d_in[12];
  const int* qidx       = (const int*)d_in[13];
  const int* idx_i      = (const int*)d_in[14];
  const int* idx_j      = (const int*)d_in[15];
  const int* maxe       = (const int*)d_in[16];

  // ---- workspace layout (no agg buffer: agg aliases out_rep) ----
  char* wp = (char*)d_ws;
  size_t used = 0;
  auto alloc = [&](size_t bytes)->char*{
    size_t pad = (bytes + 255) & ~(size_t)255;
    char* p = wp + used; used += pad; return p;
  };
  float* Qlt    = (float*)alloc((size_t)NQ*OO*4);
  float* Qrt    = (float*)alloc((size_t)NQ*OO*4);
  float* logits = (float*)alloc((size_t)NE*4);
  float* ex     = (float*)alloc((size_t)NE*4);
  float* attn   = (float*)alloc((size_t)NE*4);
  float* target = (float*)alloc((size_t)NE*4);
  u32*   segmax = (u32*)  alloc((size_t)N_NODES*4);
  float* denom  = (float*)alloc((size_t)N_NODES*4);
  int*   qcount = (int*)  alloc((size_t)NQ*4);
  int*   qstart = (int*)  alloc((size_t)NQ*4);
  int*   qcursor= (int*)  alloc((size_t)NQ*4);
  int*   bucket = (int*)  alloc((size_t)NE*4);
  int*   keep   = (int*)  alloc((size_t)NE*4);
  u16* WlH = (u16*)alloc((size_t)256*512*2); u16* WlL = (u16*)alloc((size_t)256*512*2);
  u16* WrH = (u16*)alloc((size_t)256*512*2); u16* WrL = (u16*)alloc((size_t)256*512*2);
  u16* WcH = (u16*)alloc((size_t)256*256*2); u16* WcL = (u16*)alloc((size_t)256*256*2);
  u16* WsH = (u16*)alloc((size_t)128*128*2); u16* WsL = (u16*)alloc((size_t)128*128*2);
  (void)ws_size; (void)in_sizes; (void)n_in; (void)out_size;

  float* out_score = (float*)d_out;               // f32 outputs
  float* out_rep   = (float*)d_out + N_NODES;     // also serves as agg accumulator

  hipMemsetAsync(d_out, 0, ((size_t)N_NODES + (size_t)N_NODES*DD)*4, stream);
  hipMemsetAsync(segmax, 0, (size_t)N_NODES*4, stream);
  hipMemsetAsync(denom,  0, (size_t)N_NODES*4, stream);
  hipMemsetAsync(qcount, 0, (size_t)NQ*4,      stream);
  hipMemsetAsync(keep,   0, (size_t)NE*4,      stream);

  {
    int n_all = SPL_N1 + SPL_N2 + SPL_N3 + SPL_N4;
    split_all_kernel<<<(n_all + 255)/256, 256, 0, stream>>>(Wl, Wr, Wc, Wstep,
        WlH, WlL, WrH, WrL, WcH, WcL, WsH, WsL);
  }

  qtable_kernel<<<256, 256, 0, stream>>>(qsrc, qrel, Wl, bl, Wr, br, Qlt, Qrt);

  edge_logits_kernel<<<(NE + BM - 1)/BM, 512, 0, stream>>>(node_rep, rel_emb,
      WlH, WlL, WrH, WrL, WcH, WcL, bcb, Qlt, Qrt, idx_i, idx_j, qidx,
      logits, segmax, qcount);

  seg_exp_sum_kernel<<<NE/256, 256, 0, stream>>>(logits, idx_i, segmax, ex, denom);
  scan_kernel<<<1, 64, 0, stream>>>(qcount, qstart, qcursor);
  attn_bucket_kernel<<<NE/256, 256, 0, stream>>>(ex, denom, idx_i, visited, qidx,
                                                 qcursor, bucket, attn, target);
  topk_kernel<<<NQ, 1024, 0, stream>>>(qcount, qstart, bucket, target, maxe, keep);

  edge_scatter_kernel<<<NE/4, 256, 0, stream>>>(keep, attn, target, idx_i, idx_j,
                                                node_rep, out_score, out_rep);
  final_mfma_kernel<<<(N_NODES + 63)/64, 256, 0, stream>>>(node_rep, out_rep,
                                               WsH, WsL, bstep, out_rep);
}

// Round 9
// 839.660 us; speedup vs baseline: 1.0573x; 1.0573x over previous
//
#include <hip/hip_runtime.h>

typedef unsigned short u16;
typedef unsigned int   u32;
typedef __attribute__((ext_vector_type(8))) short short8;
typedef __attribute__((ext_vector_type(4))) short short4v;
typedef __attribute__((ext_vector_type(4))) float f32x4;

#define N_NODES 100000
#define NQ      128
#define DD      128
#define NE      131072
#define OO      256   // 2*D

__device__ __forceinline__ float b2f(u16 b){ u32 u = ((u32)b) << 16; return __uint_as_float(u); }
__device__ __forceinline__ u16 f2b(float f){ u32 u = __float_as_uint(f); u32 r = (u + 0x7FFFu + ((u >> 16) & 1u)) >> 16; return (u16)r; }
__device__ __forceinline__ float lrelu(float x){ return x > 0.0f ? x : 0.01f * x; }
__device__ __forceinline__ u32 fenc(float f){ u32 u = __float_as_uint(f); return (u & 0x80000000u) ? ~u : (u | 0x80000000u); }
__device__ __forceinline__ float fdec(u32 e){ u32 u = (e & 0x80000000u) ? (e & 0x7FFFFFFFu) : ~e; return __uint_as_float(u); }

__device__ __forceinline__ void stage4(f32x4 v, u16* dhi, u16* dlo){
  short4v h4, l4;
  #pragma unroll
  for (int i = 0; i < 4; ++i){
    u16 h = f2b(v[i]); h4[i] = (short)h; l4[i] = (short)f2b(v[i] - b2f(h));
  }
  *(short4v*)dhi = h4; *(short4v*)dlo = l4;
}

__device__ __forceinline__ void cvt4(f32x4 v, short4v& h4, short4v& l4){
  #pragma unroll
  for (int i = 0; i < 4; ++i){
    u16 h = f2b(v[i]); h4[i] = (short)h; l4[i] = (short)f2b(v[i] - b2f(h));
  }
}

// ---------------- W split: all four weights, one launch ------------------------
#define SPL_N1 (256*512)
#define SPL_N2 (256*512)
#define SPL_N3 (256*256)
#define SPL_N4 (128*128)
__global__ void split_all_kernel(
    const float* __restrict__ Wl, const float* __restrict__ Wr,
    const float* __restrict__ Wc, const float* __restrict__ Ws,
    u16* __restrict__ WlH, u16* __restrict__ WlL,
    u16* __restrict__ WrH, u16* __restrict__ WrL,
    u16* __restrict__ WcH, u16* __restrict__ WcL,
    u16* __restrict__ WsH, u16* __restrict__ WsL)
{
  int i = blockIdx.x*256 + threadIdx.x;
  const float* src; u16 *hi, *lo; int k = i;
  if (k < SPL_N1){ src = Wl; hi = WlH; lo = WlL; }
  else if ((k -= SPL_N1) < SPL_N2){ src = Wr; hi = WrH; lo = WrL; }
  else if ((k -= SPL_N2) < SPL_N3){ src = Wc; hi = WcH; lo = WcL; }
  else if ((k -= SPL_N3) < SPL_N4){ src = Ws; hi = WsH; lo = WsL; }
  else return;
  float x = src[k];
  u16 h = f2b(x);
  hi[k] = h;
  lo[k] = f2b(x - b2f(h));
}

// ---------------- K0: per-query tables (exact f32) ----------------------------
__global__ __launch_bounds__(256) void qtable_kernel(
    const float* __restrict__ qsrc, const float* __restrict__ qrel,
    const float* __restrict__ Wl, const float* __restrict__ bl,
    const float* __restrict__ Wr, const float* __restrict__ br,
    float* __restrict__ Qlt, float* __restrict__ Qrt)
{
  int b = blockIdx.x; int side = b >> 7; int q = b & 127; int o = threadIdx.x;
  __shared__ __align__(16) float s[2*DD];
  if (threadIdx.x < DD) s[threadIdx.x] = qsrc[q*DD + threadIdx.x];
  else                  s[threadIdx.x] = qrel[q*DD + threadIdx.x - DD];
  __syncthreads();
  const float* W    = side ? Wr : Wl;
  const float* bias = side ? br : bl;
  float acc = bias[o];
  const float* wrow = W + (size_t)o*512 + 256;
  #pragma unroll 4
  for (int k4 = 0; k4 < 64; ++k4){
    f32x4 wv = *(const f32x4*)(wrow + k4*4);
    f32x4 sv = *(const f32x4*)(s + k4*4);
    acc += sv[0]*wv[0]; acc += sv[1]*wv[1]; acc += sv[2]*wv[2]; acc += sv[3]*wv[3];
  }
  (side ? Qrt : Qlt)[q*OO + o] = acc;
}

// ---------------- K1: fused edge bilinear -> logits (hi/lo 3-term MFMA) -------
// v6: revert to measured-best BM=64, 512 threads (R4: 284 us). Deltas vs v4:
//   - left GEMM now weight-prefetched (PF=1): VGPR headroom 64->~96 allows it.
//   - Hi pre-gather converts to bf16 hi/lo at gather time; restage = pure writes.
// LDS ~71 KB -> 2 blocks/CU (confirmed R4/R8: 3 blocks never fit; occupancy
// lever exhausted). Term-major MFMA order: bit-identical numerics.
#define BM   64
#define RSTc 264
#define HST  136

template<int WS, int PF>
__device__ __forceinline__ void gemm8(f32x4 (&ACC)[4][2],
    const u16* __restrict__ WH, const u16* __restrict__ WL,
    const u16* A0H, const u16* A0L, const u16* A1H, const u16* A1L, int ASTR,
    int ow, int ln, int qd)
{
  short8 nbh[2], nbl[2];
  if (PF){
    #pragma unroll
    for (int nt = 0; nt < 2; ++nt){ int o = ow + nt*16 + ln;
      nbh[nt] = *(const short8*)(WH + (size_t)o*WS + qd*8);
      nbl[nt] = *(const short8*)(WL + (size_t)o*WS + qd*8);
    }
  }
  #pragma unroll
  for (int c = 0; c < 8; ++c){
    short8 bh[2], bl[2], ah[4], al[4];
    if (PF){
      #pragma unroll
      for (int nt = 0; nt < 2; ++nt){ bh[nt] = nbh[nt]; bl[nt] = nbl[nt]; }
      if (c < 7){
        #pragma unroll
        for (int nt = 0; nt < 2; ++nt){ int o = ow + nt*16 + ln;
          nbh[nt] = *(const short8*)(WH + (size_t)o*WS + (c+1)*32 + qd*8);
          nbl[nt] = *(const short8*)(WL + (size_t)o*WS + (c+1)*32 + qd*8);
        }
      }
    } else {
      #pragma unroll
      for (int nt = 0; nt < 2; ++nt){ int o = ow + nt*16 + ln;
        bh[nt] = *(const short8*)(WH + (size_t)o*WS + c*32 + qd*8);
        bl[nt] = *(const short8*)(WL + (size_t)o*WS + c*32 + qd*8);
      }
    }
    const u16* hs = (c < 4) ? A0H : A1H;
    const u16* ls = (c < 4) ? A0L : A1L;
    int cc = (c < 4) ? c : c - 4;
    #pragma unroll
    for (int mt = 0; mt < 4; ++mt){
      int base = (mt*16 + ln)*ASTR + cc*32 + qd*8;
      ah[mt] = *(const short8*)&hs[base];
      al[mt] = *(const short8*)&ls[base];
    }
    #pragma unroll
    for (int mt = 0; mt < 4; ++mt)
      #pragma unroll
      for (int nt = 0; nt < 2; ++nt)
        ACC[mt][nt] = __builtin_amdgcn_mfma_f32_16x16x32_bf16(ah[mt], bh[nt], ACC[mt][nt], 0, 0, 0);
    #pragma unroll
    for (int mt = 0; mt < 4; ++mt)
      #pragma unroll
      for (int nt = 0; nt < 2; ++nt)
        ACC[mt][nt] = __builtin_amdgcn_mfma_f32_16x16x32_bf16(ah[mt], bl[nt], ACC[mt][nt], 0, 0, 0);
    #pragma unroll
    for (int mt = 0; mt < 4; ++mt)
      #pragma unroll
      for (int nt = 0; nt < 2; ++nt)
        ACC[mt][nt] = __builtin_amdgcn_mfma_f32_16x16x32_bf16(al[mt], bh[nt], ACC[mt][nt], 0, 0, 0);
  }
}

__global__ __launch_bounds__(512, 4) void edge_logits_kernel(
    const float* __restrict__ node_rep, const float* __restrict__ rel_emb,
    const u16* __restrict__ WlH, const u16* __restrict__ WlL,
    const u16* __restrict__ WrH, const u16* __restrict__ WrL,
    const u16* __restrict__ WcH, const u16* __restrict__ WcL,
    const float* __restrict__ bcb,
    const float* __restrict__ Qlt, const float* __restrict__ Qrt,
    const int* __restrict__ idx_i, const int* __restrict__ idx_j, const int* __restrict__ qidx,
    float* __restrict__ logits, u32* __restrict__ segmax, int* __restrict__ qcount)
{
  __shared__ __align__(16) u16 bufA[2*BM*HST];  // Hj -> Hi -> RRhi
  __shared__ __align__(16) u16 bufB[2*BM*HST];  // Rel -> RRlo
  __shared__ int qidS[BM];
  __shared__ float lpart[8][BM];

  u16* HjHi = bufA;  u16* HjLo = bufA + BM*HST;
  u16* ReHi = bufB;  u16* ReLo = bufB + BM*HST;
  u16* RRhi = bufA;  u16* RRlo = bufB;

  const int tid = threadIdx.x;
  const int e0 = blockIdx.x * BM;
  const int lane = tid & 63, w = tid >> 6;
  const int ln = lane & 15, qd = lane >> 4;
  const int ow = w * 32;

  if (tid < BM) qidS[tid] = qidx[e0 + tid];

  // stage Hj + Rel into LDS (hi/lo split); 2048 seg-slots over 512 threads
  #pragma unroll
  for (int it = 0; it < 4; ++it){
    int c = tid + it*512;
    int r = c >> 5, seg = (c & 31) << 2;
    int j = idx_j[e0 + r];
    f32x4 vj = *(const f32x4*)(node_rep + (size_t)j*DD + seg);
    f32x4 vr = *(const f32x4*)(rel_emb + (size_t)(e0 + r)*DD + seg);
    stage4(vj, &HjHi[r*HST + seg], &HjLo[r*HST + seg]);
    stage4(vr, &ReHi[r*HST + seg], &ReLo[r*HST + seg]);
  }
  // pre-gather Hi rows, convert to bf16 hi/lo now (restage = pure LDS writes)
  short4v hpreH[4], hpreL[4];
  #pragma unroll
  for (int it = 0; it < 4; ++it){
    int c = tid + it*512;
    int r = c >> 5, seg = (c & 31) << 2;
    f32x4 v = *(const f32x4*)(node_rep + (size_t)idx_i[e0 + r]*DD + seg);
    cvt4(v, hpreH[it], hpreL[it]);
  }
  __syncthreads();

  // ---- right GEMM: acc = [Hj|Rel] @ Wr^T ----
  f32x4 acc[4][2];
  #pragma unroll
  for (int mt = 0; mt < 4; ++mt)
    #pragma unroll
    for (int nt = 0; nt < 2; ++nt) acc[mt][nt] = (f32x4){0.f,0.f,0.f,0.f};
  gemm8<512, 1>(acc, WrH, WrL, HjHi, HjLo, ReHi, ReLo, HST, ow, ln, qd);
  __syncthreads();   // all waves done reading Hj

  // restage Hi from pre-converted registers into bufA (over Hj)
  #pragma unroll
  for (int it = 0; it < 4; ++it){
    int c = tid + it*512;
    int r = c >> 5, seg = (c & 31) << 2;
    *(short4v*)&HjHi[r*HST + seg] = hpreH[it];
    *(short4v*)&HjLo[r*HST + seg] = hpreL[it];
  }
  __syncthreads();

  // ---- left GEMM: lacc = [Hi|Rel] @ Wl^T (now prefetched too) ----
  f32x4 lacc[4][2];
  #pragma unroll
  for (int mt = 0; mt < 4; ++mt)
    #pragma unroll
    for (int nt = 0; nt < 2; ++nt) lacc[mt][nt] = (f32x4){0.f,0.f,0.f,0.f};
  gemm8<512, 1>(lacc, WlH, WlL, HjHi, HjLo, ReHi, ReLo, HST, ow, ln, qd);
  __syncthreads();   // Hi/Rel dead; RR may overlay bufA/bufB

  // epilogue: RR = leaky(acc + Qright[qid][col]); split into hi/lo in LDS
  #pragma unroll
  for (int mt = 0; mt < 4; ++mt)
    #pragma unroll
    for (int nt = 0; nt < 2; ++nt){
      int col = ow + nt*16 + ln;
      #pragma unroll
      for (int rg = 0; rg < 4; ++rg){
        int row = mt*16 + qd*4 + rg;
        float v = acc[mt][nt][rg] + Qrt[qidS[row]*OO + col];
        v = lrelu(v);
        u16 hi = f2b(v);
        RRhi[row*RSTc + col] = hi;
        RRlo[row*RSTc + col] = f2b(v - b2f(hi));
      }
    }
  __syncthreads();

  // ---- center GEMM: racc = (RRhi+RRlo) @ Wc^T ----
  f32x4 racc[4][2];
  #pragma unroll
  for (int mt = 0; mt < 4; ++mt)
    #pragma unroll
    for (int nt = 0; nt < 2; ++nt) racc[mt][nt] = (f32x4){0.f,0.f,0.f,0.f};
  gemm8<256, 1>(racc, WcH, WcL, RRhi, RRlo, RRhi + 128, RRlo + 128, RSTc, ow, ln, qd);

  // fused logits dot: sum_o leaky(L) * (R + b_center)
  float bcv[2];
  #pragma unroll
  for (int nt = 0; nt < 2; ++nt) bcv[nt] = bcb[ow + nt*16 + ln];

  float part[4][4];
  #pragma unroll
  for (int mt = 0; mt < 4; ++mt)
    #pragma unroll
    for (int rg = 0; rg < 4; ++rg) part[mt][rg] = 0.f;

  #pragma unroll
  for (int mt = 0; mt < 4; ++mt)
    #pragma unroll
    for (int nt = 0; nt < 2; ++nt){
      int col = ow + nt*16 + ln;
      #pragma unroll
      for (int rg = 0; rg < 4; ++rg){
        int row = mt*16 + qd*4 + rg;
        float lv = lacc[mt][nt][rg] + Qlt[qidS[row]*OO + col];
        lv = lrelu(lv);
        float rv = racc[mt][nt][rg] + bcv[nt];
        part[mt][rg] += lv * rv;
      }
    }

  #pragma unroll
  for (int mt = 0; mt < 4; ++mt)
    #pragma unroll
    for (int rg = 0; rg < 4; ++rg){
      float p = part[mt][rg];
      p += __shfl_xor(p, 1); p += __shfl_xor(p, 2);
      p += __shfl_xor(p, 4); p += __shfl_xor(p, 8);
      if (ln == 0) lpart[w][mt*16 + qd*4 + rg] = p;
    }
  __syncthreads();
  if (tid < BM){
    float lg = lpart[0][tid] + lpart[1][tid] + lpart[2][tid] + lpart[3][tid]
             + lpart[4][tid] + lpart[5][tid] + lpart[6][tid] + lpart[7][tid];
    int e = e0 + tid;
    logits[e] = lg;
    atomicMax(segmax + idx_i[e], fenc(lg));   // fused seg_max_count
    atomicAdd(qcount + qidx[e], 1);
  }
}

// ---------------- K2: segment exp + denom sum ----------------------------------
__global__ void seg_exp_sum_kernel(const float* __restrict__ logits,
    const int* __restrict__ idx_i, const u32* __restrict__ segmax,
    float* __restrict__ ex, float* __restrict__ denom)
{
  int e = blockIdx.x*256 + threadIdx.x; if (e >= NE) return;
  int i = idx_i[e];
  float d = fminf(logits[e] - fdec(segmax[i]), 0.0f);
  float v = expf(d);
  ex[e] = v;
  atomicAdd(denom + i, v);
}

// ---------------- K3: scan of query counts (wave-parallel Hillis-Steele) -------
__global__ __launch_bounds__(128) void scan_kernel(const int* __restrict__ qcount,
                            int* __restrict__ qstart, int* __restrict__ qcursor)
{
  __shared__ int s[NQ];
  int t = threadIdx.x;
  int mine = qcount[t];
  s[t] = mine;
  __syncthreads();
  #pragma unroll
  for (int off = 1; off < NQ; off <<= 1){
    int v = (t >= off) ? s[t - off] : 0;
    __syncthreads();
    s[t] += v;
    __syncthreads();
  }
  int excl = s[t] - mine;
  qstart[t] = excl;
  qcursor[t] = excl;
}

// ---------------- K4: fused attn/target + bucket fill --------------------------
__global__ void attn_bucket_kernel(const float* __restrict__ ex,
    const float* __restrict__ denom, const int* __restrict__ idx_i,
    const float* __restrict__ visited, const int* __restrict__ qidx,
    int* __restrict__ qcursor, int* __restrict__ bucket,
    float* __restrict__ attn, float* __restrict__ target)
{
  int e = blockIdx.x*256 + threadIdx.x; if (e >= NE) return;
  int i = idx_i[e];
  float a = ex[e] / fmaxf(denom[i], 1e-30f);
  attn[e] = a;
  target[e] = a * visited[i];
  int p = atomicAdd(qcursor + qidx[e], 1);
  bucket[p] = e;
}

// ---------------- K5: exact per-group top-k (count-beats, lexsort-stable) ------
#define TOPK_CAP 2560
__global__ __launch_bounds__(1024) void topk_kernel(
    const int* __restrict__ qcount, const int* __restrict__ qstart,
    const int* __restrict__ bucket, const float* __restrict__ target,
    const int* __restrict__ maxe_p, int* __restrict__ keep)
{
  __shared__ float ss[TOPK_CAP];
  __shared__ int   se[TOPK_CAP];
  int q = blockIdx.x;
  int m = qcount[q], start = qstart[q];
  int maxe = *maxe_p;
  if (maxe <= 0 || maxe > (1 << 30)){
    float f = __int_as_float(maxe);
    if (f > 0.0f && f < 1.0e9f) maxe = (int)f;
  }
  int tid = threadIdx.x;
  if (m <= maxe){
    for (int i = tid; i < m; i += 1024) keep[bucket[start + i]] = 1;
    return;
  }
  if (m <= TOPK_CAP){
    for (int i = tid; i < m; i += 1024){
      int e = bucket[start + i]; ss[i] = target[e]; se[i] = e;
    }
    __syncthreads();
    for (int i = tid; i < m; i += 1024){
      float s = ss[i]; int eid = se[i]; int cnt = 0;
      for (int j = 0; j < m; ++j){
        float sj = ss[j]; int ej = se[j];
        cnt += (sj > s) || (sj == s && ej < eid);
      }
      keep[eid] = (cnt < maxe) ? 1 : 0;
    }
  } else {
    for (int i = tid; i < m; i += 1024){
      int eid = bucket[start + i]; float s = target[eid]; int cnt = 0;
      for (int j = 0; j < m; ++j){
        int ej = bucket[start + j]; float sj = target[ej];
        cnt += (sj > s) || (sj == s && ej < eid);
      }
      keep[eid] = (cnt < maxe) ? 1 : 0;
    }
  }
}

// ---------------- K5b: merged scatter: score + attn-weighted hi -----------------
__global__ __launch_bounds__(256) void edge_scatter_kernel(
    const int* __restrict__ keep, const float* __restrict__ attn,
    const float* __restrict__ target,
    const int* __restrict__ idx_i, const int* __restrict__ idx_j,
    const float* __restrict__ node_rep,
    float* __restrict__ out_score, float* __restrict__ agg)
{
  int wid = (blockIdx.x * 256 + threadIdx.x) >> 6;
  if (wid >= NE) return;
  if (!keep[wid]) return;                 // wave-uniform
  int lane = threadIdx.x & 63;
  int ii = idx_i[wid], jj = idx_j[wid];
  float a = attn[wid];
  if (lane == 0) atomicAdd(out_score + jj, target[wid]);
  float h0 = node_rep[(size_t)ii*DD + lane];
  float h1 = node_rep[(size_t)ii*DD + 64 + lane];
  atomicAdd(agg + (size_t)jj*DD + lane,      a*h0);
  atomicAdd(agg + (size_t)jj*DD + 64 + lane, a*h1);
}

// ---------------- K6: out_rep = leaky((node_rep+agg) @ Wstep^T + bstep), MFMA ---
// agg aliases out_rep: each block reads its 64 rows into LDS (before barrier),
// then overwrites the same rows. Rows are disjoint across blocks -> safe.
__global__ __launch_bounds__(256) void final_mfma_kernel(
    const float* __restrict__ node_rep, const float* __restrict__ aggc,
    const u16* __restrict__ WsH, const u16* __restrict__ WsL,
    const float* __restrict__ bstep, float* __restrict__ out_rep)
{
  __shared__ __align__(16) u16 Ahi[64*HST];
  __shared__ __align__(16) u16 Alo[64*HST];
  const int tid = threadIdx.x;
  const int m0 = blockIdx.x * 64;

  for (int c = tid; c < 64*32; c += 256){
    int r = c >> 5, seg = (c & 31) << 2;
    int m = m0 + r;
    float v[4];
    if (m < N_NODES){
      const float* nr = node_rep + (size_t)m*DD + seg;
      const float* ag = aggc + (size_t)m*DD + seg;
      #pragma unroll
      for (int i = 0; i < 4; ++i) v[i] = nr[i] + ag[i];
    } else {
      #pragma unroll
      for (int i = 0; i < 4; ++i) v[i] = 0.f;
    }
    short4v h4, l4;
    #pragma unroll
    for (int i = 0; i < 4; ++i){
      u16 h = f2b(v[i]); h4[i] = (short)h; l4[i] = (short)f2b(v[i] - b2f(h));
    }
    *(short4v*)&Ahi[r*HST + seg] = h4;
    *(short4v*)&Alo[r*HST + seg] = l4;
  }
  __syncthreads();

  const int lane = tid & 63, w = tid >> 6;
  const int ln = lane & 15, qd = lane >> 4;
  const int ow = w * 32;

  short8 bh[2][4], bl[2][4];
  #pragma unroll
  for (int nt = 0; nt < 2; ++nt)
    #pragma unroll
    for (int c = 0; c < 4; ++c){
      int o = ow + nt*16 + ln;
      bh[nt][c] = *(const short8*)(WsH + (size_t)o*DD + c*32 + qd*8);
      bl[nt][c] = *(const short8*)(WsL + (size_t)o*DD + c*32 + qd*8);
    }

  f32x4 acc[4][2];
  #pragma unroll
  for (int mt = 0; mt < 4; ++mt)
    #pragma unroll
    for (int nt = 0; nt < 2; ++nt) acc[mt][nt] = (f32x4){0.f,0.f,0.f,0.f};

  #pragma unroll
  for (int mt = 0; mt < 4; ++mt)
    #pragma unroll
    for (int c = 0; c < 4; ++c){
      int base = (mt*16 + ln)*HST + c*32 + qd*8;
      short8 ah = *(const short8*)&Ahi[base];
      short8 al = *(const short8*)&Alo[base];
      #pragma unroll
      for (int nt = 0; nt < 2; ++nt){
        acc[mt][nt] = __builtin_amdgcn_mfma_f32_16x16x32_bf16(ah, bh[nt][c], acc[mt][nt], 0, 0, 0);
        acc[mt][nt] = __builtin_amdgcn_mfma_f32_16x16x32_bf16(ah, bl[nt][c], acc[mt][nt], 0, 0, 0);
        acc[mt][nt] = __builtin_amdgcn_mfma_f32_16x16x32_bf16(al, bh[nt][c], acc[mt][nt], 0, 0, 0);
      }
    }

  #pragma unroll
  for (int mt = 0; mt < 4; ++mt)
    #pragma unroll
    for (int nt = 0; nt < 2; ++nt){
      int col = ow + nt*16 + ln;
      float bs = bstep[col];
      #pragma unroll
      for (int rg = 0; rg < 4; ++rg){
        int m = m0 + mt*16 + qd*4 + rg;
        if (m < N_NODES)
          out_rep[(size_t)m*DD + col] = lrelu(acc[mt][nt][rg] + bs);
      }
    }
}

// ---------------- host ---------------------------------------------------------
extern "C" void kernel_launch(void* const* d_in, const int* in_sizes, int n_in,
                              void* d_out, int out_size, void* d_ws, size_t ws_size,
                              hipStream_t stream)
{
  const float* visited  = (const float*)d_in[0];
  const float* node_rep = (const float*)d_in[1];
  const float* qsrc     = (const float*)d_in[2];
  const float* qrel     = (const float*)d_in[3];
  const float* rel_emb  = (const float*)d_in[4];
  const float* Wl       = (const float*)d_in[5];
  const float* bl       = (const float*)d_in[6];
  const float* Wr       = (const float*)d_in[7];
  const float* br       = (const float*)d_in[8];
  const float* Wc       = (const float*)d_in[9];
  const float* bcb      = (const float*)d_in[10];
  const float* Wstep    = (const float*)d_in[11];
  const float* bstep    = (const float*)d_in[12];
  const int* qidx       = (const int*)d_in[13];
  const int* idx_i      = (const int*)d_in[14];
  const int* idx_j      = (const int*)d_in[15];
  const int* maxe       = (const int*)d_in[16];

  // ---- workspace layout (no agg buffer: agg aliases out_rep) ----
  char* wp = (char*)d_ws;
  size_t used = 0;
  auto alloc = [&](size_t bytes)->char*{
    size_t pad = (bytes + 255) & ~(size_t)255;
    char* p = wp + used; used += pad; return p;
  };
  float* Qlt    = (float*)alloc((size_t)NQ*OO*4);
  float* Qrt    = (float*)alloc((size_t)NQ*OO*4);
  float* logits = (float*)alloc((size_t)NE*4);
  float* ex     = (float*)alloc((size_t)NE*4);
  float* attn   = (float*)alloc((size_t)NE*4);
  float* target = (float*)alloc((size_t)NE*4);
  u32*   segmax = (u32*)  alloc((size_t)N_NODES*4);
  float* denom  = (float*)alloc((size_t)N_NODES*4);
  int*   qcount = (int*)  alloc((size_t)NQ*4);
  int*   qstart = (int*)  alloc((size_t)NQ*4);
  int*   qcursor= (int*)  alloc((size_t)NQ*4);
  int*   bucket = (int*)  alloc((size_t)NE*4);
  int*   keep   = (int*)  alloc((size_t)NE*4);
  u16* WlH = (u16*)alloc((size_t)256*512*2); u16* WlL = (u16*)alloc((size_t)256*512*2);
  u16* WrH = (u16*)alloc((size_t)256*512*2); u16* WrL = (u16*)alloc((size_t)256*512*2);
  u16* WcH = (u16*)alloc((size_t)256*256*2); u16* WcL = (u16*)alloc((size_t)256*256*2);
  u16* WsH = (u16*)alloc((size_t)128*128*2); u16* WsL = (u16*)alloc((size_t)128*128*2);
  (void)ws_size; (void)in_sizes; (void)n_in; (void)out_size;

  float* out_score = (float*)d_out;               // f32 outputs
  float* out_rep   = (float*)d_out + N_NODES;     // also serves as agg accumulator

  hipMemsetAsync(d_out, 0, ((size_t)N_NODES + (size_t)N_NODES*DD)*4, stream);
  hipMemsetAsync(segmax, 0, (size_t)N_NODES*4, stream);
  hipMemsetAsync(denom,  0, (size_t)N_NODES*4, stream);
  hipMemsetAsync(qcount, 0, (size_t)NQ*4,      stream);
  hipMemsetAsync(keep,   0, (size_t)NE*4,      stream);

  {
    int n_all = SPL_N1 + SPL_N2 + SPL_N3 + SPL_N4;
    split_all_kernel<<<(n_all + 255)/256, 256, 0, stream>>>(Wl, Wr, Wc, Wstep,
        WlH, WlL, WrH, WrL, WcH, WcL, WsH, WsL);
  }

  qtable_kernel<<<256, 256, 0, stream>>>(qsrc, qrel, Wl, bl, Wr, br, Qlt, Qrt);

  edge_logits_kernel<<<NE/BM, 512, 0, stream>>>(node_rep, rel_emb,
      WlH, WlL, WrH, WrL, WcH, WcL, bcb, Qlt, Qrt, idx_i, idx_j, qidx,
      logits, segmax, qcount);

  seg_exp_sum_kernel<<<NE/256, 256, 0, stream>>>(logits, idx_i, segmax, ex, denom);
  scan_kernel<<<1, 128, 0, stream>>>(qcount, qstart, qcursor);
  attn_bucket_kernel<<<NE/256, 256, 0, stream>>>(ex, denom, idx_i, visited, qidx,
                                                 qcursor, bucket, attn, target);
  topk_kernel<<<NQ, 1024, 0, stream>>>(qcount, qstart, bucket, target, maxe, keep);

  edge_scatter_kernel<<<NE/4, 256, 0, stream>>>(keep, attn, target, idx_i, idx_j,
                                                node_rep, out_score, out_rep);
  final_mfma_kernel<<<(N_NODES + 63)/64, 256, 0, stream>>>(node_rep, out_rep,
                                               WsH, WsL, bstep, out_rep);
}